// Round 1
// baseline (414.062 us; speedup 1.0000x reference)
//
#include <hip/hip_runtime.h>
#include <hip/hip_bf16.h>

using bf16x8  = __attribute__((ext_vector_type(8))) short;
using ushort8 = __attribute__((ext_vector_type(8))) unsigned short;
using f32x4   = __attribute__((ext_vector_type(4))) float;

#define DEVINL __device__ __forceinline__

DEVINL unsigned short f2bf(float f) {
    unsigned u = __builtin_bit_cast(unsigned, f);
    u += 0x7FFFu + ((u >> 16) & 1u);
    return (unsigned short)(u >> 16);
}

DEVINL void gload_lds16(const void* g, void* l) {
    __builtin_amdgcn_global_load_lds(
        (const __attribute__((address_space(1))) void*)g,
        (__attribute__((address_space(3))) void*)l, 16, 0, 0);
}

// ---------------- fp32 -> bf16 elementwise convert (8 elems/thread) --------
__global__ __launch_bounds__(256) void k_conv(const float* __restrict__ in,
                                              unsigned short* __restrict__ out,
                                              int n8) {
    int i = blockIdx.x * 256 + threadIdx.x;
    if (i >= n8) return;
    const float4* p = (const float4*)in + (size_t)i * 2;
    float4 a = p[0], b = p[1];
    ushort8 r;
    r[0] = f2bf(a.x); r[1] = f2bf(a.y); r[2] = f2bf(a.z); r[3] = f2bf(a.w);
    r[4] = f2bf(b.x); r[5] = f2bf(b.y); r[6] = f2bf(b.z); r[7] = f2bf(b.w);
    *((ushort8*)out + i) = r;
}

// ---------------- fp32 [R][C] -> bf16 [C][R] transpose ---------------------
__global__ __launch_bounds__(256) void k_convT(const float* __restrict__ in,
                                               unsigned short* __restrict__ out,
                                               int R, int C) {
    __shared__ float t[32][33];
    int c0 = blockIdx.x * 32, r0 = blockIdx.y * 32;
    int tx = threadIdx.x, ty = threadIdx.y;
#pragma unroll
    for (int i = 0; i < 4; i++)
        t[ty + i * 8][tx] = in[(size_t)(r0 + ty + i * 8) * C + c0 + tx];
    __syncthreads();
#pragma unroll
    for (int i = 0; i < 4; i++)
        out[(size_t)(c0 + ty + i * 8) * R + r0 + tx] = f2bf(t[tx][ty + i * 8]);
}

// ---------------- bf16 GEMM: C[M,N] = A[M,K] * BT[N,K]^T + bias ------------
// m97 structure: linear LDS, global_load_lds width 16, mfma 16x16x32 bf16.
template <int BM, int BN, int OUTBF>
__global__ __launch_bounds__(256) void k_gemm(const unsigned short* __restrict__ A,
                                              const unsigned short* __restrict__ BT,
                                              const float* __restrict__ bias,
                                              void* __restrict__ Cout,
                                              int M, int N, int K, float scale) {
    constexpr int WM = BM / 2, WN = BN / 2, MI = WM / 16, NI = WN / 16;
    constexpr int CA = BM * 8 / 256, CB = BN * 8 / 256;
    __shared__ unsigned short ls[(BM + BN) * 64];
    unsigned short* lsA = ls;
    unsigned short* lsB = ls + BM * 64;
    const int tid = threadIdx.x, lane = tid & 63, w = tid >> 6;
    const int m0 = blockIdx.y * BM, n0 = blockIdx.x * BN;
    const int mw = (w >> 1) * WM, nw = (w & 1) * WN;
    const int r16 = lane & 15, g4 = lane >> 4;

    f32x4 acc[MI][NI];
#pragma unroll
    for (int a = 0; a < MI; a++)
#pragma unroll
        for (int b = 0; b < NI; b++) acc[a][b] = (f32x4){0.f, 0.f, 0.f, 0.f};

    for (int k0 = 0; k0 < K; k0 += 64) {
#pragma unroll
        for (int i = 0; i < CA; i++) {
            int ch = i * 256 + w * 64 + lane;
            int row = ch >> 3, c = ch & 7;
            gload_lds16(A + (size_t)(m0 + row) * K + k0 + c * 8,
                        lsA + (size_t)(i * 256 + w * 64) * 8);
        }
#pragma unroll
        for (int i = 0; i < CB; i++) {
            int ch = i * 256 + w * 64 + lane;
            int row = ch >> 3, c = ch & 7;
            gload_lds16(BT + (size_t)(n0 + row) * K + k0 + c * 8,
                        lsB + (size_t)(i * 256 + w * 64) * 8);
        }
        __syncthreads();
#pragma unroll
        for (int kk = 0; kk < 2; kk++) {
            bf16x8 af[MI], bfr[NI];
#pragma unroll
            for (int a = 0; a < MI; a++)
                af[a] = *(const bf16x8*)&lsA[(mw + a * 16 + r16) * 64 + kk * 32 + g4 * 8];
#pragma unroll
            for (int b = 0; b < NI; b++)
                bfr[b] = *(const bf16x8*)&lsB[(nw + b * 16 + r16) * 64 + kk * 32 + g4 * 8];
#pragma unroll
            for (int a = 0; a < MI; a++)
#pragma unroll
                for (int b = 0; b < NI; b++)
                    acc[a][b] = __builtin_amdgcn_mfma_f32_16x16x32_bf16(af[a], bfr[b], acc[a][b], 0, 0, 0);
        }
        __syncthreads();
    }
#pragma unroll
    for (int b = 0; b < NI; b++) {
        int col = n0 + nw + b * 16 + r16;
        float bv = bias[col];
#pragma unroll
        for (int a = 0; a < MI; a++) {
#pragma unroll
            for (int r = 0; r < 4; r++) {
                int row = m0 + mw + a * 16 + g4 * 4 + r;
                float v = (acc[a][b][r] + bv) * scale;
                if (OUTBF)
                    ((unsigned short*)Cout)[(size_t)row * N + col] = f2bf(v);
                else
                    ((float*)Cout)[(size_t)row * N + col] = v;
            }
        }
    }
}

// ---------------- flash attention ------------------------------------------
// Q pre-scaled by 1/8. Layouts: Q/K/V/ctx as [B, len, H*64] bf16.
// 4 waves, wave w owns 16 q-rows; KV tile = 64 rows.
__global__ __launch_bounds__(256) void k_attn(const unsigned short* __restrict__ Qb,
                                              const unsigned short* __restrict__ Kb,
                                              const unsigned short* __restrict__ Vb,
                                              unsigned short* __restrict__ ctx) {
    constexpr int S = 4096, LD = 1024, PAD = 80;
    __shared__ unsigned short lsK[64 * PAD];
    __shared__ unsigned short lsVT[64 * PAD];
    __shared__ unsigned short lsP[4][16 * PAD];
    const int tid = threadIdx.x, lane = tid & 63, w = tid >> 6;
    const int r16 = lane & 15, g4 = lane >> 4;
    const int bh = blockIdx.y;
    const int b = bh >> 4, h = bh & 15;
    const int q0 = blockIdx.x * 64 + w * 16;

    const size_t qbase = ((size_t)b * 1024 + q0 + r16) * LD + h * 64;
    bf16x8 qa0 = *(const bf16x8*)&Qb[qbase + g4 * 8];
    bf16x8 qa1 = *(const bf16x8*)&Qb[qbase + 32 + g4 * 8];

    f32x4 ctxa[4];
#pragma unroll
    for (int d = 0; d < 4; d++) ctxa[d] = (f32x4){0.f, 0.f, 0.f, 0.f};
    float m_run[4], l_run[4];
#pragma unroll
    for (int r = 0; r < 4; r++) { m_run[r] = -1e30f; l_run[r] = 0.f; }

    const size_t kvbase = (size_t)b * S * LD + h * 64;

    for (int s0 = 0; s0 < S; s0 += 64) {
        // stage K (row-major) and V^T (transposed) into LDS
#pragma unroll
        for (int i = 0; i < 2; i++) {
            int ch = i * 256 + tid;
            int srow = ch >> 3, c = ch & 7;
            size_t g = kvbase + (size_t)(s0 + srow) * LD + c * 8;
            bf16x8 kv = *(const bf16x8*)&Kb[g];
            *(bf16x8*)&lsK[srow * PAD + c * 8] = kv;
            bf16x8 vv = *(const bf16x8*)&Vb[g];
#pragma unroll
            for (int j = 0; j < 8; j++)
                lsVT[(c * 8 + j) * PAD + srow] = ((unsigned short*)&vv)[j];
        }
        __syncthreads();

        // scores = Q * K^T (per wave: 16 q-rows x 64 s-cols)
        f32x4 sc[4];
#pragma unroll
        for (int ni = 0; ni < 4; ni++) sc[ni] = (f32x4){0.f, 0.f, 0.f, 0.f};
#pragma unroll
        for (int kk = 0; kk < 2; kk++) {
            bf16x8 qa = kk ? qa1 : qa0;
#pragma unroll
            for (int ni = 0; ni < 4; ni++) {
                bf16x8 kf = *(const bf16x8*)&lsK[(ni * 16 + r16) * PAD + kk * 32 + g4 * 8];
                sc[ni] = __builtin_amdgcn_mfma_f32_16x16x32_bf16(qa, kf, sc[ni], 0, 0, 0);
            }
        }

        // online softmax (rows g4*4+r, reduce across 16 lanes in group)
        unsigned short pb[4][4];
#pragma unroll
        for (int r = 0; r < 4; r++) {
            float mx = fmaxf(fmaxf(sc[0][r], sc[1][r]), fmaxf(sc[2][r], sc[3][r]));
#pragma unroll
            for (int d = 1; d < 16; d <<= 1) mx = fmaxf(mx, __shfl_xor(mx, d));
            float mn = fmaxf(m_run[r], mx);
            float corr = __expf(m_run[r] - mn);
            m_run[r] = mn;
            float rs = 0.f;
#pragma unroll
            for (int ni = 0; ni < 4; ni++) {
                float p = __expf(sc[ni][r] - mn);
                rs += p;
                pb[ni][r] = f2bf(p);
            }
#pragma unroll
            for (int d = 1; d < 16; d <<= 1) rs += __shfl_xor(rs, d);
            l_run[r] = l_run[r] * corr + rs;
#pragma unroll
            for (int di = 0; di < 4; di++) ctxa[di][r] *= corr;
        }

        // P -> per-wave LDS (C-layout -> A-fragment layout round trip)
#pragma unroll
        for (int r = 0; r < 4; r++)
#pragma unroll
            for (int ni = 0; ni < 4; ni++)
                lsP[w][(g4 * 4 + r) * PAD + ni * 16 + r16] = pb[ni][r];

        // ctx += P * V
#pragma unroll
        for (int kk = 0; kk < 2; kk++) {
            bf16x8 pa = *(const bf16x8*)&lsP[w][r16 * PAD + kk * 32 + g4 * 8];
#pragma unroll
            for (int di = 0; di < 4; di++) {
                bf16x8 vf = *(const bf16x8*)&lsVT[(di * 16 + r16) * PAD + kk * 32 + g4 * 8];
                ctxa[di] = __builtin_amdgcn_mfma_f32_16x16x32_bf16(pa, vf, ctxa[di], 0, 0, 0);
            }
        }
        __syncthreads();
    }

    // normalize + store ctx (bf16)
#pragma unroll
    for (int r = 0; r < 4; r++) {
        float inv = 1.0f / l_run[r];
        size_t obase = ((size_t)b * 1024 + q0 + g4 * 4 + r) * LD + h * 64;
#pragma unroll
        for (int di = 0; di < 4; di++)
            ctx[obase + di * 16 + r16] = f2bf(ctxa[di][r] * inv);
    }
}

// ---------------------------------------------------------------------------
extern "C" void kernel_launch(void* const* d_in, const int* in_sizes, int n_in,
                              void* d_out, int out_size, void* d_ws, size_t ws_size,
                              hipStream_t stream) {
    const float* latent = (const float*)d_in[0];
    const float* x      = (const float*)d_in[1];
    const float* Wq     = (const float*)d_in[2];
    const float* bq     = (const float*)d_in[3];
    const float* Wc     = (const float*)d_in[4];
    const float* bc     = (const float*)d_in[5];
    const float* Wk     = (const float*)d_in[6];
    const float* bk     = (const float*)d_in[7];
    const float* Wv     = (const float*)d_in[8];
    const float* bv     = (const float*)d_in[9];
    const float* Wo     = (const float*)d_in[10];
    const float* bo     = (const float*)d_in[11];
    float* out = (float*)d_out;

    char* ws = (char*)d_ws;
    size_t off = 0;
    auto alloc = [&](size_t elems) {
        void* p = ws + off;
        off += (elems * 2 + 255) & ~(size_t)255;
        return (unsigned short*)p;
    };
    unsigned short* lat_bf = alloc(2097152);   // [2,1024,1024]
    unsigned short* x_bf   = alloc(16777216);  // [2,4096,2048]
    unsigned short* WqT    = alloc(1048576);   // [1024,1024]
    unsigned short* WcT    = alloc(262144);    // [128,2048]
    unsigned short* WkT    = alloc(131072);    // [1024,128]
    unsigned short* WvT    = alloc(131072);    // [1024,128]
    unsigned short* WoT    = alloc(1048576);   // [1024,1024]
    unsigned short* comp   = alloc(1048576);   // [2,4096,128]
    unsigned short* Qb     = alloc(2097152);   // [2,1024,1024] (pre-scaled)
    unsigned short* Kb     = alloc(8388608);   // [2,4096,1024]
    unsigned short* Vb     = alloc(8388608);   // [2,4096,1024]
    unsigned short* ctxb   = alloc(2097152);   // [2,1024,1024]

    dim3 tb(32, 8);
    k_conv<<<2097152 / 2048, 256, 0, stream>>>(latent, lat_bf, 2097152 / 8);
    k_conv<<<16777216 / 2048, 256, 0, stream>>>(x, x_bf, 16777216 / 8);
    k_convT<<<dim3(1024 / 32, 1024 / 32), tb, 0, stream>>>(Wq, WqT, 1024, 1024);
    k_convT<<<dim3(128 / 32, 2048 / 32), tb, 0, stream>>>(Wc, WcT, 2048, 128);
    k_convT<<<dim3(1024 / 32, 128 / 32), tb, 0, stream>>>(Wk, WkT, 128, 1024);
    k_convT<<<dim3(1024 / 32, 128 / 32), tb, 0, stream>>>(Wv, WvT, 128, 1024);
    k_convT<<<dim3(1024 / 32, 1024 / 32), tb, 0, stream>>>(Wo, WoT, 1024, 1024);

    // compressed = x @ Wc + bc   [8192,128] (bf16)
    k_gemm<64, 64, 1><<<dim3(2, 128), 256, 0, stream>>>(x_bf, WcT, bc, comp, 8192, 128, 2048, 1.f);
    // Q = (latent @ Wq + bq) * 0.125   [2048,1024]
    k_gemm<128, 128, 1><<<dim3(8, 16), 256, 0, stream>>>(lat_bf, WqT, bq, Qb, 2048, 1024, 1024, 0.125f);
    // K = comp @ Wk + bk   [8192,1024]
    k_gemm<128, 128, 1><<<dim3(8, 64), 256, 0, stream>>>(comp, WkT, bk, Kb, 8192, 1024, 128, 1.f);
    // V = comp @ Wv + bv   [8192,1024]
    k_gemm<128, 128, 1><<<dim3(8, 64), 256, 0, stream>>>(comp, WvT, bv, Vb, 8192, 1024, 128, 1.f);
    // attention -> ctx [2048,1024]
    k_attn<<<dim3(16, 32), 256, 0, stream>>>(Qb, Kb, Vb, ctxb);
    // out = ctx @ Wo + bo (fp32)
    k_gemm<128, 128, 0><<<dim3(8, 16), 256, 0, stream>>>(ctxb, WoT, bo, out, 2048, 1024, 1024, 1.f);
}

// Round 2
// 346.403 us; speedup vs baseline: 1.1953x; 1.1953x over previous
//
#include <hip/hip_runtime.h>
#include <hip/hip_bf16.h>

using bf16x8  = __attribute__((ext_vector_type(8))) short;
using ushort8 = __attribute__((ext_vector_type(8))) unsigned short;
using f32x4   = __attribute__((ext_vector_type(4))) float;

#define DEVINL __device__ __forceinline__

DEVINL unsigned short f2bf(float f) {
    unsigned u = __builtin_bit_cast(unsigned, f);
    u += 0x7FFFu + ((u >> 16) & 1u);
    return (unsigned short)(u >> 16);
}

DEVINL void gload_lds16(const void* g, void* l) {
    __builtin_amdgcn_global_load_lds(
        (const __attribute__((address_space(1))) void*)g,
        (__attribute__((address_space(3))) void*)l, 16, 0, 0);
}

// ---------------- fp32 -> bf16 elementwise convert (8 elems/thread) --------
__global__ __launch_bounds__(256) void k_conv(const float* __restrict__ in,
                                              unsigned short* __restrict__ out,
                                              int n8) {
    int i = blockIdx.x * 256 + threadIdx.x;
    if (i >= n8) return;
    const float4* p = (const float4*)in + (size_t)i * 2;
    float4 a = p[0], b = p[1];
    ushort8 r;
    r[0] = f2bf(a.x); r[1] = f2bf(a.y); r[2] = f2bf(a.z); r[3] = f2bf(a.w);
    r[4] = f2bf(b.x); r[5] = f2bf(b.y); r[6] = f2bf(b.z); r[7] = f2bf(b.w);
    *((ushort8*)out + i) = r;
}

// ---------------- fp32 [R][C] -> bf16 [C][R] transpose ---------------------
__global__ __launch_bounds__(256) void k_convT(const float* __restrict__ in,
                                               unsigned short* __restrict__ out,
                                               int R, int C) {
    __shared__ float t[32][33];
    int c0 = blockIdx.x * 32, r0 = blockIdx.y * 32;
    int tx = threadIdx.x, ty = threadIdx.y;
#pragma unroll
    for (int i = 0; i < 4; i++)
        t[ty + i * 8][tx] = in[(size_t)(r0 + ty + i * 8) * C + c0 + tx];
    __syncthreads();
#pragma unroll
    for (int i = 0; i < 4; i++)
        out[(size_t)(c0 + ty + i * 8) * R + r0 + tx] = f2bf(t[tx][ty + i * 8]);
}

// ---------------- bf16 [b][s][h*64+d] -> bf16 [b][h][d][s] (V transpose) ---
__global__ __launch_bounds__(256) void k_vt(const unsigned short* __restrict__ V,
                                            unsigned short* __restrict__ VT) {
    __shared__ unsigned short t[32][34];
    int s0 = blockIdx.x * 32, d0 = blockIdx.y * 32, bh = blockIdx.z;
    int b = bh >> 4, h = bh & 15;
    int tx = threadIdx.x, ty = threadIdx.y;
    const unsigned short* src = V + (size_t)b * 4096 * 1024 + h * 64;
#pragma unroll
    for (int i = 0; i < 4; i++)
        t[ty + i * 8][tx] = src[(size_t)(s0 + ty + i * 8) * 1024 + d0 + tx];
    __syncthreads();
    unsigned short* dst = VT + (size_t)bh * 64 * 4096;
#pragma unroll
    for (int i = 0; i < 4; i++)
        dst[(size_t)(d0 + ty + i * 8) * 4096 + s0 + tx] = t[tx][ty + i * 8];
}

// ---------------- bf16 GEMM: C[M,N] = A[M,K] * BT[N,K]^T + bias ------------
template <int BM, int BN, int OUTBF>
__global__ __launch_bounds__(256) void k_gemm(const unsigned short* __restrict__ A,
                                              const unsigned short* __restrict__ BT,
                                              const float* __restrict__ bias,
                                              void* __restrict__ Cout,
                                              int M, int N, int K, float scale) {
    constexpr int WM = BM / 2, WN = BN / 2, MI = WM / 16, NI = WN / 16;
    constexpr int CA = BM * 8 / 256, CB = BN * 8 / 256;
    __shared__ unsigned short ls[(BM + BN) * 64];
    unsigned short* lsA = ls;
    unsigned short* lsB = ls + BM * 64;
    const int tid = threadIdx.x, lane = tid & 63, w = tid >> 6;
    const int m0 = blockIdx.y * BM, n0 = blockIdx.x * BN;
    const int mw = (w >> 1) * WM, nw = (w & 1) * WN;
    const int r16 = lane & 15, g4 = lane >> 4;

    f32x4 acc[MI][NI];
#pragma unroll
    for (int a = 0; a < MI; a++)
#pragma unroll
        for (int b = 0; b < NI; b++) acc[a][b] = (f32x4){0.f, 0.f, 0.f, 0.f};

    for (int k0 = 0; k0 < K; k0 += 64) {
#pragma unroll
        for (int i = 0; i < CA; i++) {
            int ch = i * 256 + w * 64 + lane;
            int row = ch >> 3, c = ch & 7;
            gload_lds16(A + (size_t)(m0 + row) * K + k0 + c * 8,
                        lsA + (size_t)(i * 256 + w * 64) * 8);
        }
#pragma unroll
        for (int i = 0; i < CB; i++) {
            int ch = i * 256 + w * 64 + lane;
            int row = ch >> 3, c = ch & 7;
            gload_lds16(BT + (size_t)(n0 + row) * K + k0 + c * 8,
                        lsB + (size_t)(i * 256 + w * 64) * 8);
        }
        __syncthreads();
#pragma unroll
        for (int kk = 0; kk < 2; kk++) {
            bf16x8 af[MI], bfr[NI];
#pragma unroll
            for (int a = 0; a < MI; a++)
                af[a] = *(const bf16x8*)&lsA[(mw + a * 16 + r16) * 64 + kk * 32 + g4 * 8];
#pragma unroll
            for (int b = 0; b < NI; b++)
                bfr[b] = *(const bf16x8*)&lsB[(nw + b * 16 + r16) * 64 + kk * 32 + g4 * 8];
#pragma unroll
            for (int a = 0; a < MI; a++)
#pragma unroll
                for (int b = 0; b < NI; b++)
                    acc[a][b] = __builtin_amdgcn_mfma_f32_16x16x32_bf16(af[a], bfr[b], acc[a][b], 0, 0, 0);
        }
        __syncthreads();
    }
#pragma unroll
    for (int b = 0; b < NI; b++) {
        int col = n0 + nw + b * 16 + r16;
        float bv = bias[col];
#pragma unroll
        for (int a = 0; a < MI; a++) {
#pragma unroll
            for (int r = 0; r < 4; r++) {
                int row = m0 + mw + a * 16 + g4 * 4 + r;
                float v = (acc[a][b][r] + bv) * scale;
                if (OUTBF)
                    ((unsigned short*)Cout)[(size_t)row * N + col] = f2bf(v);
                else
                    ((float*)Cout)[(size_t)row * N + col] = v;
            }
        }
    }
}

// ---------------- flash attention (S-split, swizzled LDS) ------------------
// Q pre-scaled by 1/8. Q/K: [b][len][h*64+d] bf16. VT: [b][h][d][s] bf16.
// grid (16 q-tiles, 32 bh, 4 s-chunks); 4 waves, wave w owns 16 q-rows.
// Writes UNNORMALIZED partial ctx (fp32) + per-row (m,l).
__global__ __launch_bounds__(256) void k_attn(const unsigned short* __restrict__ Qb,
                                              const unsigned short* __restrict__ Kb,
                                              const unsigned short* __restrict__ VTb,
                                              float* __restrict__ ctxp,
                                              float2* __restrict__ ML) {
    constexpr int LD = 1024;
    __shared__ unsigned short lsK[64 * 64];
    __shared__ unsigned short lsVT[64 * 64];
    __shared__ unsigned short lsP[4][16 * 64];
    const int tid = threadIdx.x, lane = tid & 63, w = tid >> 6;
    const int r16 = lane & 15, g4 = lane >> 4;
    const int bh = blockIdx.y, b = bh >> 4, h = bh & 15, z = blockIdx.z;
    const int q0 = blockIdx.x * 64 + w * 16;

    const size_t qbase = ((size_t)b * 1024 + q0 + r16) * LD + h * 64;
    bf16x8 qa0 = *(const bf16x8*)&Qb[qbase + g4 * 8];
    bf16x8 qa1 = *(const bf16x8*)&Qb[qbase + 32 + g4 * 8];

    f32x4 ctxa[4];
#pragma unroll
    for (int d = 0; d < 4; d++) ctxa[d] = (f32x4){0.f, 0.f, 0.f, 0.f};
    float m_run[4], l_run[4];
#pragma unroll
    for (int r = 0; r < 4; r++) { m_run[r] = -1e30f; l_run[r] = 0.f; }

    const size_t kbase = (size_t)b * 4096 * LD + h * 64;
    const size_t vtbase = (size_t)bh * 64 * 4096;
    const int lrow = lane >> 3;   // 0..7 within wave's 8-row stripe
    const int lcol = lane & 7;    // 16B chunk within row

    for (int s0 = z * 1024; s0 < z * 1024 + 1024; s0 += 64) {
        // stage K tile [64 s][64 d] and VT tile [64 d][64 s], linear LDS,
        // source pre-swizzled (chunk ^= row&7) so swizzled reads are clean.
#pragma unroll
        for (int i = 0; i < 2; i++) {
            int row = i * 32 + w * 8 + lrow;
            int csrc = lcol ^ (row & 7);
            gload_lds16(Kb + kbase + (size_t)(s0 + row) * LD + csrc * 8,
                        lsK + (i * 32 + w * 8) * 64);
            gload_lds16(VTb + vtbase + (size_t)row * 4096 + s0 + csrc * 8,
                        lsVT + (i * 32 + w * 8) * 64);
        }
        __syncthreads();

        // scores = Q * K^T  (per wave: 16 q-rows x 64 s-cols)
        f32x4 sc[4];
#pragma unroll
        for (int ni = 0; ni < 4; ni++) sc[ni] = (f32x4){0.f, 0.f, 0.f, 0.f};
#pragma unroll
        for (int kk = 0; kk < 2; kk++) {
            bf16x8 qa = kk ? qa1 : qa0;
#pragma unroll
            for (int ni = 0; ni < 4; ni++) {
                int row = ni * 16 + r16;
                bf16x8 kf = *(const bf16x8*)&lsK[row * 64 + (((kk * 4 + g4) ^ (row & 7)) * 8)];
                sc[ni] = __builtin_amdgcn_mfma_f32_16x16x32_bf16(qa, kf, sc[ni], 0, 0, 0);
            }
        }

        // online softmax (rows g4*4+r, reduce across 16 lanes in group)
        unsigned short pb[4][4];
#pragma unroll
        for (int r = 0; r < 4; r++) {
            float mx = fmaxf(fmaxf(sc[0][r], sc[1][r]), fmaxf(sc[2][r], sc[3][r]));
#pragma unroll
            for (int d = 1; d < 16; d <<= 1) mx = fmaxf(mx, __shfl_xor(mx, d));
            float mn = fmaxf(m_run[r], mx);
            float corr = __expf(m_run[r] - mn);
            m_run[r] = mn;
            float rs = 0.f;
#pragma unroll
            for (int ni = 0; ni < 4; ni++) {
                float p = __expf(sc[ni][r] - mn);
                rs += p;
                pb[ni][r] = f2bf(p);
            }
#pragma unroll
            for (int d = 1; d < 16; d <<= 1) rs += __shfl_xor(rs, d);
            l_run[r] = l_run[r] * corr + rs;
#pragma unroll
            for (int di = 0; di < 4; di++) ctxa[di][r] *= corr;
        }

        // P -> per-wave LDS (swizzled; same involution as reads)
#pragma unroll
        for (int r = 0; r < 4; r++) {
            int q = g4 * 4 + r;
#pragma unroll
            for (int ni = 0; ni < 4; ni++) {
                int c = (ni * 2 + (r16 >> 3)) ^ (q & 7);
                lsP[w][q * 64 + c * 8 + (r16 & 7)] = pb[ni][r];
            }
        }

        // ctx += P * V   (B-operand rows = VT rows, swizzled reads)
#pragma unroll
        for (int kk = 0; kk < 2; kk++) {
            bf16x8 pa = *(const bf16x8*)&lsP[w][r16 * 64 + (((kk * 4 + g4) ^ (r16 & 7)) * 8)];
#pragma unroll
            for (int di = 0; di < 4; di++) {
                int row = di * 16 + r16;
                bf16x8 vf = *(const bf16x8*)&lsVT[row * 64 + (((kk * 4 + g4) ^ (row & 7)) * 8)];
                ctxa[di] = __builtin_amdgcn_mfma_f32_16x16x32_bf16(pa, vf, ctxa[di], 0, 0, 0);
            }
        }
        __syncthreads();
    }

    // store unnormalized partials + (m,l)
    float* cp = ctxp + ((size_t)z * 2 + b) * 1024 * 1024;
#pragma unroll
    for (int r = 0; r < 4; r++) {
        int q = q0 + g4 * 4 + r;
#pragma unroll
        for (int di = 0; di < 4; di++)
            cp[(size_t)q * 1024 + h * 64 + di * 16 + r16] = ctxa[di][r];
    }
    if (r16 == 0) {
#pragma unroll
        for (int r = 0; r < 4; r++)
            ML[(((size_t)z * 2 + b) * 16 + h) * 1024 + q0 + g4 * 4 + r] =
                make_float2(m_run[r], l_run[r]);
    }
}

// ---------------- merge 4 S-chunks -----------------------------------------
__global__ __launch_bounds__(256) void k_merge(const float* __restrict__ ctxp,
                                               const float2* __restrict__ ML,
                                               unsigned short* __restrict__ ctx) {
    int gid = blockIdx.x * 256 + threadIdx.x;      // 262144 threads
    int d8 = gid & 7, h = (gid >> 3) & 15, q = (gid >> 7) & 1023, b = gid >> 17;
    float m[4], l[4];
#pragma unroll
    for (int z = 0; z < 4; z++) {
        float2 e = ML[(((size_t)z * 2 + b) * 16 + h) * 1024 + q];
        m[z] = e.x; l[z] = e.y;
    }
    float M = fmaxf(fmaxf(m[0], m[1]), fmaxf(m[2], m[3]));
    float wz[4], L = 0.f;
#pragma unroll
    for (int z = 0; z < 4; z++) { wz[z] = __expf(m[z] - M); L += wz[z] * l[z]; }
    float inv = 1.0f / L;
    float o[8];
#pragma unroll
    for (int j = 0; j < 8; j++) o[j] = 0.f;
#pragma unroll
    for (int z = 0; z < 4; z++) {
        const float4* p = (const float4*)(ctxp + ((size_t)z * 2 + b) * 1048576 +
                                          (size_t)q * 1024 + h * 64 + d8 * 8);
        float4 a = p[0], c = p[1];
        o[0] += wz[z] * a.x; o[1] += wz[z] * a.y; o[2] += wz[z] * a.z; o[3] += wz[z] * a.w;
        o[4] += wz[z] * c.x; o[5] += wz[z] * c.y; o[6] += wz[z] * c.z; o[7] += wz[z] * c.w;
    }
    ushort8 r;
#pragma unroll
    for (int j = 0; j < 8; j++) r[j] = f2bf(o[j] * inv);
    *(ushort8*)&ctx[((size_t)b * 1024 + q) * 1024 + h * 64 + d8 * 8] = r;
}

// ---------------------------------------------------------------------------
extern "C" void kernel_launch(void* const* d_in, const int* in_sizes, int n_in,
                              void* d_out, int out_size, void* d_ws, size_t ws_size,
                              hipStream_t stream) {
    const float* latent = (const float*)d_in[0];
    const float* x      = (const float*)d_in[1];
    const float* Wq     = (const float*)d_in[2];
    const float* bq     = (const float*)d_in[3];
    const float* Wc     = (const float*)d_in[4];
    const float* bc     = (const float*)d_in[5];
    const float* Wk     = (const float*)d_in[6];
    const float* bk     = (const float*)d_in[7];
    const float* Wv     = (const float*)d_in[8];
    const float* bv     = (const float*)d_in[9];
    const float* Wo     = (const float*)d_in[10];
    const float* bo     = (const float*)d_in[11];
    float* out = (float*)d_out;

    char* ws = (char*)d_ws;
    size_t off = 0;
    auto alloc = [&](size_t shorts) {
        void* p = ws + off;
        off += (shorts * 2 + 255) & ~(size_t)255;
        return (unsigned short*)p;
    };
    unsigned short* lat_bf = alloc(2097152);   // [2,1024,1024]
    unsigned short* x_bf   = alloc(16777216);  // [2,4096,2048]
    unsigned short* WqT    = alloc(1048576);
    unsigned short* WcT    = alloc(262144);
    unsigned short* WkT    = alloc(131072);
    unsigned short* WvT    = alloc(131072);
    unsigned short* WoT    = alloc(1048576);
    unsigned short* comp   = alloc(1048576);   // [2,4096,128]
    unsigned short* Qb     = alloc(2097152);   // pre-scaled Q
    unsigned short* Kb     = alloc(8388608);   // [2,4096,1024]
    unsigned short* Vb     = alloc(8388608);   // [2,4096,1024]
    unsigned short* VTb    = alloc(8388608);   // [2,16,64,4096]
    unsigned short* ctxb   = alloc(2097152);   // [2,1024,1024]
    float*          ctxp   = (float*)alloc(16777216);  // [4,2,1024,1024] fp32
    float2*         MLp    = (float2*)alloc(524288);   // [4,2,16,1024] float2

    dim3 tb(32, 8);
    k_conv<<<2097152 / 2048, 256, 0, stream>>>(latent, lat_bf, 2097152 / 8);
    k_conv<<<16777216 / 2048, 256, 0, stream>>>(x, x_bf, 16777216 / 8);
    k_convT<<<dim3(1024 / 32, 1024 / 32), tb, 0, stream>>>(Wq, WqT, 1024, 1024);
    k_convT<<<dim3(128 / 32, 2048 / 32), tb, 0, stream>>>(Wc, WcT, 2048, 128);
    k_convT<<<dim3(1024 / 32, 128 / 32), tb, 0, stream>>>(Wk, WkT, 128, 1024);
    k_convT<<<dim3(1024 / 32, 128 / 32), tb, 0, stream>>>(Wv, WvT, 128, 1024);
    k_convT<<<dim3(1024 / 32, 1024 / 32), tb, 0, stream>>>(Wo, WoT, 1024, 1024);

    // compressed = x @ Wc + bc   [8192,128]
    k_gemm<64, 64, 1><<<dim3(2, 128), 256, 0, stream>>>(x_bf, WcT, bc, comp, 8192, 128, 2048, 1.f);
    // Q = (latent @ Wq + bq)/8   [2048,1024]  (64^2 tiles -> 512 blocks)
    k_gemm<64, 64, 1><<<dim3(16, 32), 256, 0, stream>>>(lat_bf, WqT, bq, Qb, 2048, 1024, 1024, 0.125f);
    // K/V = comp @ Wk/Wv   [8192,1024]
    k_gemm<128, 128, 1><<<dim3(8, 64), 256, 0, stream>>>(comp, WkT, bk, Kb, 8192, 1024, 128, 1.f);
    k_gemm<128, 128, 1><<<dim3(8, 64), 256, 0, stream>>>(comp, WvT, bv, Vb, 8192, 1024, 128, 1.f);
    // V -> VT [b][h][d][s]
    k_vt<<<dim3(128, 2, 32), tb, 0, stream>>>(Vb, VTb);
    // attention partials (4 S-chunks) + merge
    k_attn<<<dim3(16, 32, 4), 256, 0, stream>>>(Qb, Kb, VTb, ctxp, MLp);
    k_merge<<<1024, 256, 0, stream>>>(ctxp, MLp, ctxb);
    // out = ctx @ Wo + bo (fp32, 64^2 tiles -> 512 blocks)
    k_gemm<64, 64, 0><<<dim3(16, 32), 256, 0, stream>>>(ctxb, WoT, bo, out, 2048, 1024, 1024, 1.f);
}

// Round 3
// 308.991 us; speedup vs baseline: 1.3400x; 1.1211x over previous
//
#include <hip/hip_runtime.h>
#include <hip/hip_bf16.h>

using bf16x8  = __attribute__((ext_vector_type(8))) short;
using ushort8 = __attribute__((ext_vector_type(8))) unsigned short;
using f32x4   = __attribute__((ext_vector_type(4))) float;

#define DEVINL __device__ __forceinline__

DEVINL unsigned short f2bf(float f) {
    unsigned u = __builtin_bit_cast(unsigned, f);
    u += 0x7FFFu + ((u >> 16) & 1u);
    return (unsigned short)(u >> 16);
}

DEVINL void gload_lds16(const void* g, void* l) {
    __builtin_amdgcn_global_load_lds(
        (const __attribute__((address_space(1))) void*)g,
        (__attribute__((address_space(3))) void*)l, 16, 0, 0);
}

// ---------------- fp32 -> bf16 elementwise convert (8 elems/thread) --------
__global__ __launch_bounds__(256) void k_conv(const float* __restrict__ in,
                                              unsigned short* __restrict__ out,
                                              int n8) {
    int i = blockIdx.x * 256 + threadIdx.x;
    if (i >= n8) return;
    const float4* p = (const float4*)in + (size_t)i * 2;
    float4 a = p[0], b = p[1];
    ushort8 r;
    r[0] = f2bf(a.x); r[1] = f2bf(a.y); r[2] = f2bf(a.z); r[3] = f2bf(a.w);
    r[4] = f2bf(b.x); r[5] = f2bf(b.y); r[6] = f2bf(b.z); r[7] = f2bf(b.w);
    *((ushort8*)out + i) = r;
}

// ---------------- fp32 [R][C] -> bf16 [C][R] transpose ---------------------
__global__ __launch_bounds__(256) void k_convT(const float* __restrict__ in,
                                               unsigned short* __restrict__ out,
                                               int R, int C) {
    __shared__ float t[32][33];
    int c0 = blockIdx.x * 32, r0 = blockIdx.y * 32;
    int tx = threadIdx.x, ty = threadIdx.y;
#pragma unroll
    for (int i = 0; i < 4; i++)
        t[ty + i * 8][tx] = in[(size_t)(r0 + ty + i * 8) * C + c0 + tx];
    __syncthreads();
#pragma unroll
    for (int i = 0; i < 4; i++)
        out[(size_t)(c0 + ty + i * 8) * R + r0 + tx] = f2bf(t[tx][ty + i * 8]);
}

// ---------------- bf16 GEMM: C[M,N] = A[M,K] * BT[N,K]^T + bias ------------
// BIASROW: bias indexed by output row (for the direct-V^T GEMM).
template <int BM, int BN, int OUTBF, int BIASROW>
__global__ __launch_bounds__(256) void k_gemm(const unsigned short* __restrict__ A,
                                              const unsigned short* __restrict__ BT,
                                              const float* __restrict__ bias,
                                              void* __restrict__ Cout,
                                              int M, int N, int K, float scale) {
    constexpr int WM = BM / 2, WN = BN / 2, MI = WM / 16, NI = WN / 16;
    constexpr int CA = BM * 8 / 256, CB = BN * 8 / 256;
    __shared__ unsigned short ls[(BM + BN) * 64];
    unsigned short* lsA = ls;
    unsigned short* lsB = ls + BM * 64;
    const int tid = threadIdx.x, lane = tid & 63, w = tid >> 6;
    const int m0 = blockIdx.y * BM, n0 = blockIdx.x * BN;
    const int mw = (w >> 1) * WM, nw = (w & 1) * WN;
    const int r16 = lane & 15, g4 = lane >> 4;

    f32x4 acc[MI][NI];
#pragma unroll
    for (int a = 0; a < MI; a++)
#pragma unroll
        for (int b = 0; b < NI; b++) acc[a][b] = (f32x4){0.f, 0.f, 0.f, 0.f};

    for (int k0 = 0; k0 < K; k0 += 64) {
#pragma unroll
        for (int i = 0; i < CA; i++) {
            int ch = i * 256 + w * 64 + lane;
            int row = ch >> 3, c = ch & 7;
            gload_lds16(A + (size_t)(m0 + row) * K + k0 + c * 8,
                        lsA + (size_t)(i * 256 + w * 64) * 8);
        }
#pragma unroll
        for (int i = 0; i < CB; i++) {
            int ch = i * 256 + w * 64 + lane;
            int row = ch >> 3, c = ch & 7;
            gload_lds16(BT + (size_t)(n0 + row) * K + k0 + c * 8,
                        lsB + (size_t)(i * 256 + w * 64) * 8);
        }
        __syncthreads();
#pragma unroll
        for (int kk = 0; kk < 2; kk++) {
            bf16x8 af[MI], bfr[NI];
#pragma unroll
            for (int a = 0; a < MI; a++)
                af[a] = *(const bf16x8*)&lsA[(mw + a * 16 + r16) * 64 + kk * 32 + g4 * 8];
#pragma unroll
            for (int b = 0; b < NI; b++)
                bfr[b] = *(const bf16x8*)&lsB[(nw + b * 16 + r16) * 64 + kk * 32 + g4 * 8];
#pragma unroll
            for (int a = 0; a < MI; a++)
#pragma unroll
                for (int b = 0; b < NI; b++)
                    acc[a][b] = __builtin_amdgcn_mfma_f32_16x16x32_bf16(af[a], bfr[b], acc[a][b], 0, 0, 0);
        }
        __syncthreads();
    }
#pragma unroll
    for (int b = 0; b < NI; b++) {
        int col = n0 + nw + b * 16 + r16;
        float bvc = BIASROW ? 0.f : bias[col];
#pragma unroll
        for (int a = 0; a < MI; a++) {
#pragma unroll
            for (int r = 0; r < 4; r++) {
                int row = m0 + mw + a * 16 + g4 * 4 + r;
                float bv = BIASROW ? bias[row] : bvc;
                float v = (acc[a][b][r] + bv) * scale;
                if (OUTBF)
                    ((unsigned short*)Cout)[(size_t)row * N + col] = f2bf(v);
                else
                    ((float*)Cout)[(size_t)row * N + col] = v;
            }
        }
    }
}

// ---------------- flash attention (swapped QK^T, 2-phase prefetch) ---------
// Q pre-scaled by 0.125*log2(e); softmax in exp2 domain.
// Q/K: [b][len][h*64+d] bf16. VT: [b*16+h][d][s] bf16.
// grid (16 q-tiles, 32 bh, 4 s-chunks); 4 waves, wave w owns 16 q-rows.
// Writes UNNORMALIZED partial ctx (fp32) + per-row (m,l) in exp2 domain.
__global__ __launch_bounds__(256) void k_attn(const unsigned short* __restrict__ Qb,
                                              const unsigned short* __restrict__ Kb,
                                              const unsigned short* __restrict__ VTb,
                                              float* __restrict__ ctxp,
                                              float2* __restrict__ ML) {
    constexpr int LD = 1024;
    __shared__ unsigned short lsK[2][64 * 64];
    __shared__ unsigned short lsVT[2][64 * 64];
    __shared__ unsigned short lsP[4][16 * 64];
    const int tid = threadIdx.x, lane = tid & 63, w = tid >> 6;
    const int r16 = lane & 15, g4 = lane >> 4;
    const int bh = blockIdx.y, b = bh >> 4, h = bh & 15, z = blockIdx.z;
    const int q0 = blockIdx.x * 64 + w * 16;

    const size_t qbase = ((size_t)b * 1024 + q0 + r16) * LD + h * 64;
    bf16x8 qa0 = *(const bf16x8*)&Qb[qbase + g4 * 8];
    bf16x8 qa1 = *(const bf16x8*)&Qb[qbase + 32 + g4 * 8];

    f32x4 ctxa[4];
#pragma unroll
    for (int d = 0; d < 4; d++) ctxa[d] = (f32x4){0.f, 0.f, 0.f, 0.f};
    float m_run = -1e30f, l_run = 0.f;   // per-lane state for q = q0 + r16

    const size_t kbase = (size_t)b * 4096 * LD + h * 64;
    const size_t vtbase = (size_t)bh * 64 * 4096;
    const int lrow = lane >> 3;   // 0..7
    const int lcol = lane & 7;

    // stage K tile [64 s][64 d] and VT tile [64 d][64 s] into buf; source
    // pre-swizzled (chunk ^= row&7), linear LDS dest (rule 21 involution).
    auto STAGE = [&](int bufi, int s0) {
#pragma unroll
        for (int i = 0; i < 2; i++) {
            int row = i * 32 + w * 8 + lrow;
            int csrc = lcol ^ (row & 7);
            gload_lds16(Kb + kbase + (size_t)(s0 + row) * LD + csrc * 8,
                        &lsK[bufi][(i * 32 + w * 8) * 64]);
            gload_lds16(VTb + vtbase + (size_t)row * 4096 + s0 + csrc * 8,
                        &lsVT[bufi][(i * 32 + w * 8) * 64]);
        }
    };

    auto COMPUTE = [&](int bufi) {
        // S^T = K * Q^T  (per wave: 64 s-rows x 16 q-cols); lane owns q=r16
        f32x4 sc[4];
#pragma unroll
        for (int ni = 0; ni < 4; ni++) sc[ni] = (f32x4){0.f, 0.f, 0.f, 0.f};
        __builtin_amdgcn_s_setprio(1);
#pragma unroll
        for (int kk = 0; kk < 2; kk++) {
            bf16x8 qa = kk ? qa1 : qa0;
#pragma unroll
            for (int ni = 0; ni < 4; ni++) {
                int row = ni * 16 + r16;
                bf16x8 kf = *(const bf16x8*)&lsK[bufi][row * 64 + (((kk * 4 + g4) ^ (row & 7)) * 8)];
                sc[ni] = __builtin_amdgcn_mfma_f32_16x16x32_bf16(kf, qa, sc[ni], 0, 0, 0);
            }
        }
        __builtin_amdgcn_s_setprio(0);

        // online softmax: 16 s-values per lane, reduce across 4 lane-groups
        float pmax = sc[0][0];
#pragma unroll
        for (int ni = 0; ni < 4; ni++)
#pragma unroll
            for (int r = 0; r < 4; r++)
                if (ni || r) pmax = fmaxf(pmax, sc[ni][r]);
        pmax = fmaxf(pmax, __shfl_xor(pmax, 16));
        pmax = fmaxf(pmax, __shfl_xor(pmax, 32));
        float mn = fmaxf(m_run, pmax);
        float corr = exp2f(m_run - mn);
        m_run = mn;
        float p[4][4];
        float rs = 0.f;
#pragma unroll
        for (int ni = 0; ni < 4; ni++)
#pragma unroll
            for (int r = 0; r < 4; r++) {
                p[ni][r] = exp2f(sc[ni][r] - mn);
                rs += p[ni][r];
            }
        rs += __shfl_xor(rs, 16);
        rs += __shfl_xor(rs, 32);
        l_run = l_run * corr + rs;

        // rescale ctx: rows q' = g4*4+r need corr from lane q'
        float corr4[4];
#pragma unroll
        for (int r = 0; r < 4; r++) corr4[r] = __shfl(corr, g4 * 4 + r);
#pragma unroll
        for (int di = 0; di < 4; di++)
#pragma unroll
            for (int r = 0; r < 4; r++) ctxa[di][r] *= corr4[r];

        // P -> per-wave LDS: value s = ni*16+g4*4+reg at row q=r16 (swizzled)
#pragma unroll
        for (int ni = 0; ni < 4; ni++) {
            int sw = (ni * 2 + (g4 >> 1)) ^ (r16 & 7);
            int base = r16 * 64 + sw * 8 + (g4 & 1) * 4;
#pragma unroll
            for (int pr = 0; pr < 2; pr++) {
                unsigned u;
                asm("v_cvt_pk_bf16_f32 %0, %1, %2"
                    : "=v"(u) : "v"(p[ni][2 * pr]), "v"(p[ni][2 * pr + 1]));
                *(unsigned*)&lsP[w][base + pr * 2] = u;
            }
        }

        // ctx += P * V
        __builtin_amdgcn_s_setprio(1);
#pragma unroll
        for (int kk = 0; kk < 2; kk++) {
            bf16x8 pa = *(const bf16x8*)&lsP[w][r16 * 64 + (((kk * 4 + g4) ^ (r16 & 7)) * 8)];
#pragma unroll
            for (int di = 0; di < 4; di++) {
                int row = di * 16 + r16;
                bf16x8 vf = *(const bf16x8*)&lsVT[bufi][row * 64 + (((kk * 4 + g4) ^ (row & 7)) * 8)];
                ctxa[di] = __builtin_amdgcn_mfma_f32_16x16x32_bf16(pa, vf, ctxa[di], 0, 0, 0);
            }
        }
        __builtin_amdgcn_s_setprio(0);
    };

    const int s_base = z * 1024;
    STAGE(0, s_base);
    __syncthreads();
#pragma unroll 1
    for (int tt = 0; tt < 8; tt++) {
        int t0 = tt * 2;
        STAGE(1, s_base + (t0 + 1) * 64);   // t0 <= 14, always valid
        COMPUTE(0);
        __syncthreads();
        if (t0 + 2 < 16) STAGE(0, s_base + (t0 + 2) * 64);
        COMPUTE(1);
        __syncthreads();
    }

    // store unnormalized partials + (m,l)
    float* cp = ctxp + ((size_t)z * 2 + b) * 1024 * 1024;
#pragma unroll
    for (int r = 0; r < 4; r++) {
        int q = q0 + g4 * 4 + r;
#pragma unroll
        for (int di = 0; di < 4; di++)
            cp[(size_t)q * 1024 + h * 64 + di * 16 + r16] = ctxa[di][r];
    }
    if (g4 == 0)
        ML[(((size_t)z * 2 + b) * 16 + h) * 1024 + q0 + r16] = make_float2(m_run, l_run);
}

// ---------------- merge 4 S-chunks (exp2 domain) ---------------------------
__global__ __launch_bounds__(256) void k_merge(const float* __restrict__ ctxp,
                                               const float2* __restrict__ ML,
                                               unsigned short* __restrict__ ctx) {
    int gid = blockIdx.x * 256 + threadIdx.x;      // 262144 threads
    int d8 = gid & 7, h = (gid >> 3) & 15, q = (gid >> 7) & 1023, b = gid >> 17;
    float m[4], l[4];
#pragma unroll
    for (int z = 0; z < 4; z++) {
        float2 e = ML[(((size_t)z * 2 + b) * 16 + h) * 1024 + q];
        m[z] = e.x; l[z] = e.y;
    }
    float M = fmaxf(fmaxf(m[0], m[1]), fmaxf(m[2], m[3]));
    float wz[4], L = 0.f;
#pragma unroll
    for (int z = 0; z < 4; z++) { wz[z] = exp2f(m[z] - M); L += wz[z] * l[z]; }
    float inv = 1.0f / L;
    float o[8];
#pragma unroll
    for (int j = 0; j < 8; j++) o[j] = 0.f;
#pragma unroll
    for (int z = 0; z < 4; z++) {
        const float4* p = (const float4*)(ctxp + ((size_t)z * 2 + b) * 1048576 +
                                          (size_t)q * 1024 + h * 64 + d8 * 8);
        float4 a = p[0], c = p[1];
        o[0] += wz[z] * a.x; o[1] += wz[z] * a.y; o[2] += wz[z] * a.z; o[3] += wz[z] * a.w;
        o[4] += wz[z] * c.x; o[5] += wz[z] * c.y; o[6] += wz[z] * c.z; o[7] += wz[z] * c.w;
    }
    ushort8 r;
#pragma unroll
    for (int j = 0; j < 8; j++) r[j] = f2bf(o[j] * inv);
    *(ushort8*)&ctx[((size_t)b * 1024 + q) * 1024 + h * 64 + d8 * 8] = r;
}

// ---------------------------------------------------------------------------
extern "C" void kernel_launch(void* const* d_in, const int* in_sizes, int n_in,
                              void* d_out, int out_size, void* d_ws, size_t ws_size,
                              hipStream_t stream) {
    const float* latent = (const float*)d_in[0];
    const float* x      = (const float*)d_in[1];
    const float* Wq     = (const float*)d_in[2];
    const float* bq     = (const float*)d_in[3];
    const float* Wc     = (const float*)d_in[4];
    const float* bc     = (const float*)d_in[5];
    const float* Wk     = (const float*)d_in[6];
    const float* bk     = (const float*)d_in[7];
    const float* Wv     = (const float*)d_in[8];
    const float* bv     = (const float*)d_in[9];
    const float* Wo     = (const float*)d_in[10];
    const float* bo     = (const float*)d_in[11];
    float* out = (float*)d_out;

    char* ws = (char*)d_ws;
    size_t off = 0;
    auto alloc = [&](size_t shorts) {
        void* p = ws + off;
        off += (shorts * 2 + 255) & ~(size_t)255;
        return (unsigned short*)p;
    };
    unsigned short* lat_bf = alloc(2097152);   // [2,1024,1024]
    unsigned short* x_bf   = alloc(16777216);  // [2,4096,2048]
    unsigned short* WqT    = alloc(1048576);
    unsigned short* WcT    = alloc(262144);
    unsigned short* WkT    = alloc(131072);
    unsigned short* WvT    = alloc(131072);
    unsigned short* WoT    = alloc(1048576);
    unsigned short* comp   = alloc(1048576);   // [2,4096,128]
    unsigned short* Qb     = alloc(2097152);   // pre-scaled Q (x 0.125*log2e)
    unsigned short* Kb     = alloc(8388608);   // [2,4096,1024]
    unsigned short* VTb    = alloc(8388608);   // [2*16,64,4096]
    unsigned short* ctxb   = alloc(2097152);   // [2,1024,1024]
    float*          ctxp   = (float*)alloc(16777216);  // [4,2,1024,1024] fp32
    float2*         MLp    = (float2*)alloc(524288);   // [4,2,16,1024] float2

    dim3 tb(32, 8);
    k_conv<<<2097152 / 2048, 256, 0, stream>>>(latent, lat_bf, 2097152 / 8);
    k_conv<<<16777216 / 2048, 256, 0, stream>>>(x, x_bf, 16777216 / 8);
    k_convT<<<dim3(1024 / 32, 1024 / 32), tb, 0, stream>>>(Wq, WqT, 1024, 1024);
    k_convT<<<dim3(128 / 32, 2048 / 32), tb, 0, stream>>>(Wc, WcT, 2048, 128);
    k_convT<<<dim3(1024 / 32, 128 / 32), tb, 0, stream>>>(Wk, WkT, 128, 1024);
    k_convT<<<dim3(1024 / 32, 128 / 32), tb, 0, stream>>>(Wv, WvT, 128, 1024);
    k_convT<<<dim3(1024 / 32, 1024 / 32), tb, 0, stream>>>(Wo, WoT, 1024, 1024);

    // compressed = x @ Wc + bc   [8192,128]
    k_gemm<64, 64, 1, 0><<<dim3(2, 128), 256, 0, stream>>>(x_bf, WcT, bc, comp, 8192, 128, 2048, 1.f);
    // Q = (latent @ Wq + bq) * 0.125*log2(e)   [2048,1024]
    k_gemm<64, 64, 1, 0><<<dim3(16, 32), 256, 0, stream>>>(lat_bf, WqT, bq, Qb, 2048, 1024, 1024, 0.18033688f);
    // K = comp @ Wk + bk   [8192,1024]
    k_gemm<128, 128, 1, 0><<<dim3(8, 64), 256, 0, stream>>>(comp, WkT, bk, Kb, 8192, 1024, 128, 1.f);
    // V^T directly: VT_b[hd][s] = sum_k WvT[hd][k] * comp_b[s][k] + bv[hd]
    k_gemm<64, 64, 1, 1><<<dim3(64, 16), 256, 0, stream>>>(WvT, comp, bv, VTb, 1024, 4096, 128, 1.f);
    k_gemm<64, 64, 1, 1><<<dim3(64, 16), 256, 0, stream>>>(WvT, comp + 4096 * 128, bv,
                                                           VTb + (size_t)16 * 64 * 4096, 1024, 4096, 128, 1.f);
    // attention partials (4 S-chunks) + merge
    k_attn<<<dim3(16, 32, 4), 256, 0, stream>>>(Qb, Kb, VTb, ctxp, MLp);
    k_merge<<<1024, 256, 0, stream>>>(ctxp, MLp, ctxb);
    // out = ctx @ Wo + bo (fp32)
    k_gemm<64, 64, 0, 0><<<dim3(16, 32), 256, 0, stream>>>(ctxb, WoT, bo, out, 2048, 1024, 1024, 1.f);
}

// Round 4
// 284.136 us; speedup vs baseline: 1.4573x; 1.0875x over previous
//
#include <hip/hip_runtime.h>
#include <hip/hip_bf16.h>

using bf16x8  = __attribute__((ext_vector_type(8))) short;
using ushort8 = __attribute__((ext_vector_type(8))) unsigned short;
using f32x4   = __attribute__((ext_vector_type(4))) float;

#define DEVINL __device__ __forceinline__

DEVINL unsigned short f2bf(float f) {
    unsigned u = __builtin_bit_cast(unsigned, f);
    u += 0x7FFFu + ((u >> 16) & 1u);
    return (unsigned short)(u >> 16);
}

DEVINL void gload_lds16(const void* g, void* l) {
    __builtin_amdgcn_global_load_lds(
        (const __attribute__((address_space(1))) void*)g,
        (__attribute__((address_space(3))) void*)l, 16, 0, 0);
}

// ---------------- fp32 -> bf16 convert, two tensors in one launch ----------
__global__ __launch_bounds__(256) void k_conv(const float* __restrict__ a,
                                              unsigned short* __restrict__ oa, int n8a,
                                              const float* __restrict__ bsrc,
                                              unsigned short* __restrict__ ob, int n8b) {
    int i = blockIdx.x * 256 + threadIdx.x;
    const float* src;
    unsigned short* dst;
    if (i < n8a) { src = a + (size_t)i * 8; dst = oa + (size_t)i * 8; }
    else {
        int j = i - n8a;
        if (j >= n8b) return;
        src = bsrc + (size_t)j * 8; dst = ob + (size_t)j * 8;
    }
    float4 A = *(const float4*)src, B = *(const float4*)(src + 4);
    ushort8 r;
    r[0] = f2bf(A.x); r[1] = f2bf(A.y); r[2] = f2bf(A.z); r[3] = f2bf(A.w);
    r[4] = f2bf(B.x); r[5] = f2bf(B.y); r[6] = f2bf(B.z); r[7] = f2bf(B.w);
    *(ushort8*)dst = r;
}

// ---------------- fp32 [R][C] -> bf16 [C][R] transpose, z-batched ----------
__global__ __launch_bounds__(256) void k_convT(const float* __restrict__ i0,
                                               unsigned short* __restrict__ o0,
                                               const float* __restrict__ i1,
                                               unsigned short* __restrict__ o1,
                                               int R, int C) {
    __shared__ float t[32][33];
    const float* in = blockIdx.z ? i1 : i0;
    unsigned short* out = blockIdx.z ? o1 : o0;
    int c0 = blockIdx.x * 32, r0 = blockIdx.y * 32;
    int tx = threadIdx.x, ty = threadIdx.y;
#pragma unroll
    for (int i = 0; i < 4; i++)
        t[ty + i * 8][tx] = in[(size_t)(r0 + ty + i * 8) * C + c0 + tx];
    __syncthreads();
#pragma unroll
    for (int i = 0; i < 4; i++)
        out[(size_t)(c0 + ty + i * 8) * R + r0 + tx] = f2bf(t[tx][ty + i * 8]);
}

// ---------------- bf16 GEMM, 2-phase prefetch ------------------------------
// C[M,N] = A[M,K] * BT[N,K]^T + bias; z-batched via element strides.
template <int BM, int BN, int OUTBF, int BIASROW>
__global__ __launch_bounds__(256) void k_gemm(const unsigned short* __restrict__ A,
                                              const unsigned short* __restrict__ BT,
                                              const float* __restrict__ bias,
                                              void* __restrict__ Cout,
                                              int M, int N, int K, float scale,
                                              size_t zA, size_t zB, size_t zC) {
    constexpr int WM = BM / 2, WN = BN / 2, MI = WM / 16, NI = WN / 16;
    constexpr int CA = BM * 8 / 256, CB = BN * 8 / 256;
    __shared__ unsigned short ls[2][(BM + BN) * 64];
    const int tid = threadIdx.x, lane = tid & 63, w = tid >> 6;
    const int m0 = blockIdx.y * BM, n0 = blockIdx.x * BN, zz = blockIdx.z;
    const int mw = (w >> 1) * WM, nw = (w & 1) * WN;
    const int r16 = lane & 15, g4 = lane >> 4;
    A += zA * zz; BT += zB * zz;

    f32x4 acc[MI][NI];
#pragma unroll
    for (int a = 0; a < MI; a++)
#pragma unroll
        for (int b = 0; b < NI; b++) acc[a][b] = (f32x4){0.f, 0.f, 0.f, 0.f};

    auto STAGE = [&](int bufi, int k0) {
        unsigned short* lsA = ls[bufi];
        unsigned short* lsB = ls[bufi] + BM * 64;
#pragma unroll
        for (int i = 0; i < CA; i++) {
            int ch = i * 256 + w * 64 + lane;
            int row = ch >> 3, c = ch & 7;
            gload_lds16(A + (size_t)(m0 + row) * K + k0 + c * 8,
                        lsA + (size_t)(i * 256 + w * 64) * 8);
        }
#pragma unroll
        for (int i = 0; i < CB; i++) {
            int ch = i * 256 + w * 64 + lane;
            int row = ch >> 3, c = ch & 7;
            gload_lds16(BT + (size_t)(n0 + row) * K + k0 + c * 8,
                        lsB + (size_t)(i * 256 + w * 64) * 8);
        }
    };
    auto COMPUTE = [&](int bufi) {
        const unsigned short* lsA = ls[bufi];
        const unsigned short* lsB = ls[bufi] + BM * 64;
#pragma unroll
        for (int kk = 0; kk < 2; kk++) {
            bf16x8 af[MI], bfr[NI];
#pragma unroll
            for (int a = 0; a < MI; a++)
                af[a] = *(const bf16x8*)&lsA[(mw + a * 16 + r16) * 64 + kk * 32 + g4 * 8];
#pragma unroll
            for (int b = 0; b < NI; b++)
                bfr[b] = *(const bf16x8*)&lsB[(nw + b * 16 + r16) * 64 + kk * 32 + g4 * 8];
#pragma unroll
            for (int a = 0; a < MI; a++)
#pragma unroll
                for (int b = 0; b < NI; b++)
                    acc[a][b] = __builtin_amdgcn_mfma_f32_16x16x32_bf16(af[a], bfr[b], acc[a][b], 0, 0, 0);
        }
    };

    const int nk = K >> 6;
    STAGE(0, 0);
    __syncthreads();
    for (int t = 0; t < nk; ++t) {
        if (t + 1 < nk) STAGE((t + 1) & 1, (t + 1) << 6);
        COMPUTE(t & 1);
        __syncthreads();
    }

#pragma unroll
    for (int b = 0; b < NI; b++) {
        int col = n0 + nw + b * 16 + r16;
        float bvc = BIASROW ? 0.f : bias[col];
#pragma unroll
        for (int a = 0; a < MI; a++) {
#pragma unroll
            for (int r = 0; r < 4; r++) {
                int row = m0 + mw + a * 16 + g4 * 4 + r;
                float bv = BIASROW ? bias[row] : bvc;
                float v = (acc[a][b][r] + bv) * scale;
                if (OUTBF)
                    ((unsigned short*)Cout)[zC * zz + (size_t)row * N + col] = f2bf(v);
                else
                    ((float*)Cout)[zC * zz + (size_t)row * N + col] = v;
            }
        }
    }
}

// ---------------- flash attention ------------------------------------------
// Q pre-scaled by 0.125*log2(e); exp2-domain softmax; swapped QK^T.
// Q/K: [b][len][h*64+d] bf16. VT: [b*16+h][d][s] bf16.
// 1-D grid 1536, XCD-swizzled: 16 q-blocks of one (bh,z) per XCD.
// z in {0,1,2} covers s-tiles [z*64/3, (z+1)*64/3).
__global__ __launch_bounds__(256, 4) void k_attn(const unsigned short* __restrict__ Qb,
                                                 const unsigned short* __restrict__ Kb,
                                                 const unsigned short* __restrict__ VTb,
                                                 float* __restrict__ ctxp,
                                                 float2* __restrict__ ML) {
    constexpr int LD = 1024;
    __shared__ unsigned short lsK[2][64 * 64];
    __shared__ unsigned short lsVT[2][64 * 64];
    __shared__ unsigned short lsP[4][16 * 64];
    const int tid = threadIdx.x, lane = tid & 63, w = tid >> 6;
    const int r16 = lane & 15, g4 = lane >> 4;
    // decode wg = xcd + 8*(qi + 16*gg); g = gg*8+xcd -> (bh, z)
    const int wg = blockIdx.x;
    const int xcd = wg & 7, t_ = wg >> 3, qi = t_ & 15, gg = t_ >> 4;
    const int g = gg * 8 + xcd;
    const int bh = g & 31, z = g >> 5;
    const int b = bh >> 4, h = bh & 15;
    const int q0 = qi * 64 + w * 16;

    const size_t qbase = ((size_t)b * 1024 + q0 + r16) * LD + h * 64;
    bf16x8 qa0 = *(const bf16x8*)&Qb[qbase + g4 * 8];
    bf16x8 qa1 = *(const bf16x8*)&Qb[qbase + 32 + g4 * 8];

    f32x4 ctxa[4];
#pragma unroll
    for (int d = 0; d < 4; d++) ctxa[d] = (f32x4){0.f, 0.f, 0.f, 0.f};
    float m_run = -1e30f, l_run = 0.f;   // per-lane, q = q0 + r16

    // lane-constant swizzled offsets (elements). row&7 == r16&7 for all
    // 16-row strides, so 2 offsets serve every K/VT/P ds_read.
    const int s7 = r16 & 7;
    const int offk0 = r16 * 64 + ((g4 ^ s7) << 3);
    const int offk1 = r16 * 64 + (((g4 + 4) ^ s7) << 3);
    const int pwb = r16 * 64 + (g4 & 1) * 4;
    const int c2 = g4 >> 1;
    const int swn0 = ((0 + c2) ^ s7) << 3, swn1 = ((2 + c2) ^ s7) << 3;
    const int swn2 = ((4 + c2) ^ s7) << 3, swn3 = ((6 + c2) ^ s7) << 3;

    // staging bases: row = i*32 + w*8 + lrow, csrc = lcol ^ lrow (row&7==lrow)
    const int lrow = lane >> 3, lcol = lane & 7;
    const int csrc = lcol ^ lrow;
    const unsigned short* gK = Kb + (size_t)b * 4096 * LD + h * 64 +
                               (size_t)(w * 8 + lrow) * LD + csrc * 8;
    const unsigned short* gV = VTb + (size_t)bh * 64 * 4096 +
                               (size_t)(w * 8 + lrow) * 4096 + csrc * 8;

    auto STAGE = [&](int bufi, int s0) {
        gload_lds16(gK + (size_t)s0 * LD, &lsK[bufi][(w * 8) * 64]);
        gload_lds16(gK + (size_t)(s0 + 32) * LD, &lsK[bufi][(32 + w * 8) * 64]);
        gload_lds16(gV + s0, &lsVT[bufi][(w * 8) * 64]);
        gload_lds16(gV + s0 + 32 * 4096, &lsVT[bufi][(32 + w * 8) * 64]);
    };

    auto COMPUTE = [&](int bufi) {
        // S^T = K * Q^T : lane owns q=r16, 16 s-values
        f32x4 sc[4];
#pragma unroll
        for (int ni = 0; ni < 4; ni++) sc[ni] = (f32x4){0.f, 0.f, 0.f, 0.f};
        __builtin_amdgcn_s_setprio(1);
#pragma unroll
        for (int kk = 0; kk < 2; kk++) {
            bf16x8 qa = kk ? qa1 : qa0;
            int ofk = kk ? offk1 : offk0;
#pragma unroll
            for (int ni = 0; ni < 4; ni++) {
                bf16x8 kf = *(const bf16x8*)&lsK[bufi][ni * 1024 + ofk];
                sc[ni] = __builtin_amdgcn_mfma_f32_16x16x32_bf16(kf, qa, sc[ni], 0, 0, 0);
            }
        }
        __builtin_amdgcn_s_setprio(0);

        float pmax = sc[0][0];
#pragma unroll
        for (int ni = 0; ni < 4; ni++)
#pragma unroll
            for (int r = 0; r < 4; r++)
                if (ni || r) pmax = fmaxf(pmax, sc[ni][r]);
        pmax = fmaxf(pmax, __shfl_xor(pmax, 16));
        pmax = fmaxf(pmax, __shfl_xor(pmax, 32));

        // defer-max (T13): rescale only when max grew by > 8 (exp2 domain)
        if (!__all(pmax <= m_run + 8.f)) {
            float mn = fmaxf(m_run, pmax);
            float corr = exp2f(m_run - mn);
            m_run = mn;
            l_run *= corr;
            float c4[4];
#pragma unroll
            for (int r = 0; r < 4; r++) c4[r] = __shfl(corr, g4 * 4 + r);
#pragma unroll
            for (int di = 0; di < 4; di++)
#pragma unroll
                for (int r = 0; r < 4; r++) ctxa[di][r] *= c4[r];
        }

        float p[4][4];
        float rs = 0.f;
#pragma unroll
        for (int ni = 0; ni < 4; ni++)
#pragma unroll
            for (int r = 0; r < 4; r++) {
                p[ni][r] = exp2f(sc[ni][r] - m_run);
                rs += p[ni][r];
            }
        rs += __shfl_xor(rs, 16);
        rs += __shfl_xor(rs, 32);
        l_run += rs;

        // P -> per-wave LDS, swizzled, one 8B write per ni
#pragma unroll
        for (int ni = 0; ni < 4; ni++) {
            int sw = ni == 0 ? swn0 : ni == 1 ? swn1 : ni == 2 ? swn2 : swn3;
            unsigned u0, u1;
            asm("v_cvt_pk_bf16_f32 %0, %1, %2" : "=v"(u0) : "v"(p[ni][0]), "v"(p[ni][1]));
            asm("v_cvt_pk_bf16_f32 %0, %1, %2" : "=v"(u1) : "v"(p[ni][2]), "v"(p[ni][3]));
            *(uint2*)&lsP[w][pwb + sw] = make_uint2(u0, u1);
        }

        // ctx += P * V
        __builtin_amdgcn_s_setprio(1);
#pragma unroll
        for (int kk = 0; kk < 2; kk++) {
            int ofk = kk ? offk1 : offk0;
            bf16x8 pa = *(const bf16x8*)&lsP[w][ofk];
#pragma unroll
            for (int di = 0; di < 4; di++) {
                bf16x8 vf = *(const bf16x8*)&lsVT[bufi][di * 1024 + ofk];
                ctxa[di] = __builtin_amdgcn_mfma_f32_16x16x32_bf16(pa, vf, ctxa[di], 0, 0, 0);
            }
        }
        __builtin_amdgcn_s_setprio(0);
    };

    const int t0 = (z * 64) / 3, t1 = ((z + 1) * 64) / 3;
    STAGE(0, t0 * 64);
    __syncthreads();
#pragma unroll 1
    for (int t = t0; t < t1; ++t) {
        int pb = (t - t0) & 1;
        if (t + 1 < t1) STAGE(pb ^ 1, (t + 1) * 64);
        COMPUTE(pb);
        __syncthreads();
    }

    float* cp = ctxp + ((size_t)z * 2 + b) * 1024 * 1024;
#pragma unroll
    for (int r = 0; r < 4; r++) {
        int q = q0 + g4 * 4 + r;
#pragma unroll
        for (int di = 0; di < 4; di++)
            cp[(size_t)q * 1024 + h * 64 + di * 16 + r16] = ctxa[di][r];
    }
    if (g4 == 0)
        ML[(((size_t)z * 2 + b) * 16 + h) * 1024 + q0 + r16] = make_float2(m_run, l_run);
}

// ---------------- merge 3 S-chunks (exp2 domain) ---------------------------
__global__ __launch_bounds__(256) void k_merge(const float* __restrict__ ctxp,
                                               const float2* __restrict__ ML,
                                               unsigned short* __restrict__ ctx) {
    int gid = blockIdx.x * 256 + threadIdx.x;      // 262144 threads
    int d8 = gid & 7, h = (gid >> 3) & 15, q = (gid >> 7) & 1023, b = gid >> 17;
    float m[3], l[3];
#pragma unroll
    for (int z = 0; z < 3; z++) {
        float2 e = ML[(((size_t)z * 2 + b) * 16 + h) * 1024 + q];
        m[z] = e.x; l[z] = e.y;
    }
    float M = fmaxf(fmaxf(m[0], m[1]), m[2]);
    float wz[3], L = 0.f;
#pragma unroll
    for (int z = 0; z < 3; z++) { wz[z] = exp2f(m[z] - M); L += wz[z] * l[z]; }
    float inv = 1.0f / L;
    float o[8];
#pragma unroll
    for (int j = 0; j < 8; j++) o[j] = 0.f;
#pragma unroll
    for (int z = 0; z < 3; z++) {
        const float4* p = (const float4*)(ctxp + ((size_t)z * 2 + b) * 1048576 +
                                          (size_t)q * 1024 + h * 64 + d8 * 8);
        float4 a = p[0], c = p[1];
        o[0] += wz[z] * a.x; o[1] += wz[z] * a.y; o[2] += wz[z] * a.z; o[3] += wz[z] * a.w;
        o[4] += wz[z] * c.x; o[5] += wz[z] * c.y; o[6] += wz[z] * c.z; o[7] += wz[z] * c.w;
    }
    ushort8 r;
#pragma unroll
    for (int j = 0; j < 8; j++) r[j] = f2bf(o[j] * inv);
    *(ushort8*)&ctx[((size_t)b * 1024 + q) * 1024 + h * 64 + d8 * 8] = r;
}

// ---------------------------------------------------------------------------
extern "C" void kernel_launch(void* const* d_in, const int* in_sizes, int n_in,
                              void* d_out, int out_size, void* d_ws, size_t ws_size,
                              hipStream_t stream) {
    const float* latent = (const float*)d_in[0];
    const float* x      = (const float*)d_in[1];
    const float* Wq     = (const float*)d_in[2];
    const float* bq     = (const float*)d_in[3];
    const float* Wc     = (const float*)d_in[4];
    const float* bc     = (const float*)d_in[5];
    const float* Wk     = (const float*)d_in[6];
    const float* bk     = (const float*)d_in[7];
    const float* Wv     = (const float*)d_in[8];
    const float* bv     = (const float*)d_in[9];
    const float* Wo     = (const float*)d_in[10];
    const float* bo     = (const float*)d_in[11];
    float* out = (float*)d_out;

    char* ws = (char*)d_ws;
    size_t off = 0;
    auto alloc = [&](size_t shorts) {
        void* p = ws + off;
        off += (shorts * 2 + 255) & ~(size_t)255;
        return (unsigned short*)p;
    };
    unsigned short* lat_bf = alloc(2097152);   // [2,1024,1024]
    unsigned short* x_bf   = alloc(16777216);  // [2,4096,2048]
    unsigned short* WqT    = alloc(1048576);
    unsigned short* WcT    = alloc(262144);
    unsigned short* WkT    = alloc(131072);
    unsigned short* WvT    = alloc(131072);
    unsigned short* WoT    = alloc(1048576);
    unsigned short* comp   = alloc(1048576);   // [2,4096,128]
    unsigned short* Qb     = alloc(2097152);   // pre-scaled Q (x 0.125*log2e)
    unsigned short* Kb     = alloc(8388608);   // [2,4096,1024]
    unsigned short* VTb    = alloc(8388608);   // [2*16,64,4096]
    unsigned short* ctxb   = alloc(2097152);   // [2,1024,1024]
    float*          ctxp   = (float*)alloc(12582912);  // [3,2,1024,1024] fp32
    float2*         MLp    = (float2*)alloc(393216);   // [3,2,16,1024] float2

    dim3 tb(32, 8);
    // conversions: latent + x in one launch
    k_conv<<<9216, 256, 0, stream>>>(latent, lat_bf, 262144, x, x_bf, 2097152);
    // weight transposes: (Wq,Wo), (Wk,Wv), Wc
    k_convT<<<dim3(32, 32, 2), tb, 0, stream>>>(Wq, WqT, Wo, WoT, 1024, 1024);
    k_convT<<<dim3(32, 4, 2), tb, 0, stream>>>(Wk, WkT, Wv, WvT, 128, 1024);
    k_convT<<<dim3(4, 64, 1), tb, 0, stream>>>(Wc, WcT, Wc, WcT, 2048, 128);

    // compressed = x @ Wc + bc   [8192,128]  (32x128 tiles, 256 blocks)
    k_gemm<32, 128, 1, 0><<<dim3(1, 256, 1), 256, 0, stream>>>(
        x_bf, WcT, bc, comp, 8192, 128, 2048, 1.f, 0, 0, 0);
    // Q = (latent @ Wq + bq) * 0.125*log2(e)   [2048,1024]
    k_gemm<64, 64, 1, 0><<<dim3(16, 32, 1), 256, 0, stream>>>(
        lat_bf, WqT, bq, Qb, 2048, 1024, 1024, 0.18033688f, 0, 0, 0);
    // K = comp @ Wk + bk   [8192,1024]
    k_gemm<128, 128, 1, 0><<<dim3(8, 64, 1), 256, 0, stream>>>(
        comp, WkT, bk, Kb, 8192, 1024, 128, 1.f, 0, 0, 0);
    // V^T direct, z-batched over b: VT_b[hd][s] = WvT[hd][:] . comp_b[s][:] + bv[hd]
    k_gemm<64, 64, 1, 1><<<dim3(64, 16, 2), 256, 0, stream>>>(
        WvT, comp, bv, VTb, 1024, 4096, 128, 1.f,
        0, (size_t)4096 * 128, (size_t)16 * 64 * 4096);
    // attention partials (3 S-chunks, XCD-swizzled 1-D grid) + merge
    k_attn<<<1536, 256, 0, stream>>>(Qb, Kb, VTb, ctxp, MLp);
    k_merge<<<1024, 256, 0, stream>>>(ctxp, MLp, ctxb);
    // out = ctx @ Wo + bo (fp32)
    k_gemm<64, 64, 0, 0><<<dim3(16, 32, 1), 256, 0, stream>>>(
        ctxb, WoT, bo, out, 2048, 1024, 1024, 1.f, 0, 0, 0);
}